// Round 9
// baseline (559.781 us; speedup 1.0000x reference)
//
#include <hip/hip_runtime.h>
#include <math.h>

#define NN 32768
#define NE 524288

// overflow-safe softplus(x) - ln2 using HW exp2/log2 (v_exp_f32 / v_log_f32)
__device__ __forceinline__ float sspf(float x) {
    const float INVLN2 = 1.4426950408889634f;
    const float LN2    = 0.69314718055994530942f;
    float t = __builtin_amdgcn_exp2f(-fabsf(x) * INVLN2);
    return fmaxf(x, 0.0f) + LN2 * __builtin_amdgcn_logf(1.0f + t) - LN2;
}

// ---------------- CSR build ----------------
// rank[e] = arrival order of edge e within its segment (atomic return).
__global__ __launch_bounds__(256) void hist_kernel(
    const int* __restrict__ idx_i, int* __restrict__ counts, int* __restrict__ rank)
{
    int e = blockIdx.x * 256 + threadIdx.x;
    rank[e] = atomicAdd(&counts[idx_i[e]], 1);
}

// single block, 1024 threads, 32 counts each; writes start[0..NN] and a
// degree-sorted (descending) node order for nodeagg load balance.
__global__ __launch_bounds__(1024) void scan_kernel(
    const int* __restrict__ counts, int* __restrict__ start, int* __restrict__ order)
{
    __shared__ int tmp[1024];
    __shared__ int bins[64];
    __shared__ int bcur[64];
    int tid = threadIdx.x;
    int base = tid * 32;
    int cnt[32];
    int local[32];
    int sum = 0;
    const int4* c4 = (const int4*)(counts + base);
#pragma unroll
    for (int q = 0; q < 8; q++) {
        int4 v = c4[q];
        cnt[q*4+0] = v.x; cnt[q*4+1] = v.y; cnt[q*4+2] = v.z; cnt[q*4+3] = v.w;
        local[q*4+0] = sum; sum += v.x;
        local[q*4+1] = sum; sum += v.y;
        local[q*4+2] = sum; sum += v.z;
        local[q*4+3] = sum; sum += v.w;
    }
    tmp[tid] = sum;
    __syncthreads();
    for (int off = 1; off < 1024; off <<= 1) {
        int v = 0;
        if (tid >= off) v = tmp[tid - off];
        __syncthreads();
        if (tid >= off) tmp[tid] += v;
        __syncthreads();
    }
    int excl = tmp[tid] - sum;
#pragma unroll
    for (int k = 0; k < 32; k++) {
        start[base + k] = excl + local[k];
    }
    if (tid == 1023) start[NN] = tmp[1023];

    // ---- descending-degree counting sort -> order[] ----
    if (tid < 64) bins[tid] = 0;
    __syncthreads();
#pragma unroll
    for (int k = 0; k < 32; k++) {
        int d = cnt[k] > 63 ? 63 : cnt[k];
        atomicAdd(&bins[63 - d], 1);
    }
    __syncthreads();
    if (tid == 0) {
        int run = 0;
        for (int b = 0; b < 64; b++) { int c = bins[b]; bcur[b] = run; run += c; }
    }
    __syncthreads();
#pragma unroll
    for (int k = 0; k < 32; k++) {
        int d = cnt[k] > 63 ? 63 : cnt[k];
        int pos = atomicAdd(&bcur[63 - d], 1);
        order[pos] = base + k;
    }
}

// ---------------- eorder: CSR slot -> edge id (4B scatter, L2-absorbed) ----
__global__ __launch_bounds__(256) void eorder_kernel(
    const int* __restrict__ idx_i, const int* __restrict__ start,
    const int* __restrict__ rank, int* __restrict__ eorder)
{
    int e = blockIdx.x * 256 + threadIdx.x;
    eorder[start[idx_i[e]] + rank[e]] = e;
}

// ---------------- node embedding ----------------
// interleaved output layout: embed[n*64 + f*4 + {0,1,2,3}] = {s1, v1x, v1y, v1z}
// so nodeagg fetches one float4 per (edge, lane).
// Staging loops are CHUNKED (#pragma unroll 1) to cap live registers.
__global__ __launch_bounds__(256) void embed_kernel(
    const float* __restrict__ x,
    const float* __restrict__ W1s,   // (64,16)
    const float* __restrict__ W1v,   // (32,16)
    float* __restrict__ embed)
{
    __shared__ float sWs[1024];
    __shared__ float sWv[512];
    int t = threadIdx.x;
    for (int k = t; k < 1024; k += 256) sWs[k] = W1s[k];
    for (int k = t; k < 512;  k += 256) sWv[k] = W1v[k];
    __syncthreads();

    int n = blockIdx.x * 256 + t;
    const float* xr = x + (size_t)n * 160;

    float s1[16];
#pragma unroll
    for (int f = 0; f < 16; f++) s1[f] = 0.f;
#pragma unroll 1
    for (int cc = 0; cc < 4; cc++) {
        float4 sv[4];
#pragma unroll
        for (int q = 0; q < 4; q++) sv[q] = ((const float4*)xr)[cc*4 + q];
#pragma unroll
        for (int q = 0; q < 4; q++) {
            int c = (cc*4 + q) * 4;
#pragma unroll
            for (int f = 0; f < 16; f++) {
                s1[f] += sv[q].x * sWs[(c+0)*16+f] + sv[q].y * sWs[(c+1)*16+f]
                       + sv[q].z * sWs[(c+2)*16+f] + sv[q].w * sWs[(c+3)*16+f];
            }
        }
    }

    float v1[48];
#pragma unroll
    for (int k = 0; k < 48; k++) v1[k] = 0.f;
    // 96 vector components = 4 chunks x 24 (= 8 columns x 3 dims each chunk)
#pragma unroll 1
    for (int cc = 0; cc < 4; cc++) {
        float4 vv[6];
#pragma unroll
        for (int q = 0; q < 6; q++) vv[q] = ((const float4*)(xr + 64))[cc*6 + q];
#pragma unroll
        for (int q = 0; q < 6; q++) {
            float vals[4] = {vv[q].x, vv[q].y, vv[q].z, vv[q].w};
#pragma unroll
            for (int u = 0; u < 4; u++) {
                int ml = q * 4 + u;         // 0..23, static
                int c = cc * 8 + ml / 3;    // runtime base + static
                int d = ml % 3;             // static
                float val = vals[u];
#pragma unroll
                for (int f = 0; f < 16; f++)
                    v1[f*3+d] += val * sWv[c*16+f];
            }
        }
    }

    float ob[64];
    const float is32 = 0.17677669529663688f;
#pragma unroll
    for (int f = 0; f < 16; f++) {
        ob[f*4+0] = s1[f] * 0.125f;
        ob[f*4+1] = v1[f*3+0] * is32;
        ob[f*4+2] = v1[f*3+1] * is32;
        ob[f*4+3] = v1[f*3+2] * is32;
    }

    float4* eo = (float4*)(embed + (size_t)n * 64);
#pragma unroll
    for (int q = 0; q < 16; q++) eo[q] = ((float4*)ob)[q];
}

// ---------------- FUSED filter-MLP + node aggregation ----------------
// 16 threads per node (4 nodes per wave), thread owns a single f.
// No epack intermediate: per edge, lane f loads float2 of the f_ij row
// (16 lanes = the full 128B line, coalesced), computes h[f] with the fv
// values broadcast via __shfl within the group, applies sspf*rc, then the
// w-dots consume h[k] via __shfl. mW2 weights (64) live in REGISTERS
// (launch_bounds(256,4) -> 128-VGPR budget); mW1 in LDS (conflict-free:
// lane f reads sW1[r*16+f], consecutive lanes -> consecutive banks).
// Nodes processed in descending-degree order (order[]), CSR order via
// eorder[] -> identical accumulation order to previous rounds.
__global__ __launch_bounds__(256, 4) void nodeagg_kernel(
    const float* __restrict__ embed,   // (N,64) interleaved (f*4+{s,x,y,z})
    const float* __restrict__ f_ij,    // (E,32)
    const float* __restrict__ rcut_ij, // (E,)
    const float* __restrict__ Yr,      // (E,4)
    const int*   __restrict__ idx_j,   // (E,)
    const int*   __restrict__ start,   // (N+1,)
    const int*   __restrict__ order,   // (N,) degree-sorted node ids
    const int*   __restrict__ eorder,  // (E,) CSR slot -> edge id
    const float* __restrict__ mW1,     // (32,16)
    const float* __restrict__ mb1,     // (16,)
    const float* __restrict__ mW2,     // (16,96)
    const float* __restrict__ mb2,     // (96,)
    float* __restrict__ acc)           // (N,128) planar
{
    __shared__ float sW1[512];
    __shared__ float sb1[16];
    int t = threadIdx.x;
    for (int k = t; k < 512; k += 256) sW1[k] = mW1[k];
    if (t < 16) sb1[t] = mb1[t];
    __syncthreads();

    int gid = blockIdx.x * 256 + t;
    int node = order[gid >> 4];
    int f = gid & 15;
    int lane = t & 63;
    int gb = lane & 48;               // group base lane for shfl

    float wga[16], wgb[16], wgc[16], wgd[16];
#pragma unroll
    for (int k = 0; k < 16; k++) {
        wga[k] = mW2[k*96 + f];
        wgb[k] = mW2[k*96 + 16 + f];
        wgc[k] = mW2[k*96 + 32 + f];
        wgd[k] = mW2[k*96 + 48 + f];
    }
    float b0a = mb2[f], b0b = mb2[16+f], b1a = mb2[32+f], b1b = mb2[48+f];
    float b1f = sb1[f];

    float aa = 0.f, ab = 0.f;
    float A1a0 = 0.f, A1a1 = 0.f, A1a2 = 0.f;
    float A1b0 = 0.f, A1b1 = 0.f, A1b2 = 0.f;

    int s0 = start[node];
    int s1 = start[node+1];

    for (int q = s0; q < s1; q++) {
        int e = eorder[q];
        float2 fv = *(const float2*)(f_ij + (size_t)e * 32 + 2*f);
        float4 y  = ((const float4*)Yr)[e];      // group-uniform broadcast
        float rc  = rcut_ij[e];
        int j     = idx_j[e];
        float4 e4 = ((const float4*)(embed + (size_t)j * 64))[f];

        // h[f] = ssp(b1[f] + sum_r fv[r]*mW1[r][f]) * rc
        float hf = b1f;
#pragma unroll
        for (int k = 0; k < 16; k++) {
            float a0 = __shfl(fv.x, gb + k, 64);   // fv[2k]
            float a1 = __shfl(fv.y, gb + k, 64);   // fv[2k+1]
            hf += a0 * sW1[(2*k)*16 + f] + a1 * sW1[(2*k+1)*16 + f];
        }
        hf = sspf(hf) * rc;

        float w0a = rc*b0a, w0b = rc*b0b, w1a = rc*b1a, w1b = rc*b1b;
#pragma unroll
        for (int k = 0; k < 16; k++) {
            float hk = __shfl(hf, gb + k, 64);
            w0a += hk * wga[k];
            w0b += hk * wgb[k];
            w1a += hk * wgc[k];
            w1b += hk * wgd[k];
        }

        float sj = e4.x, vx = e4.y, vy = e4.z, vz = e4.w;
        aa += sj * y.x * w0a;
        ab += (vx*y.y + vy*y.z + vz*y.w) * w0b;
        float sw = sj * w1a;
        A1a0 += sw * y.y;
        A1a1 += sw * y.z;
        A1a2 += sw * y.w;
        float yw = y.x * w1b;
        A1b0 += vx * yw;
        A1b1 += vy * yw;
        A1b2 += vz * yw;
    }

    const float is3 = 0.5773502691896258f;   // 1/sqrt(3)
    float* o = acc + (size_t)node * 128;
    o[f]       = aa;
    o[16 + f]  = ab * is3;
    o[32 + f]  = A1a0;
    o[48 + f]  = A1a1;
    o[64 + f]  = A1a2;
    o[80 + f]  = A1b0;
    o[96 + f]  = A1b1;
    o[112 + f] = A1b2;
}

// ---------------- node output ----------------
// 64 nodes per block (lane = node), 512 threads = 8 waves (balanced roles):
// waves 0-3: s-chain, 16 cols each (s2 k=32, s3 k=64)
// waves 4-7: v-chain, 24 col-dims each over flattened cd = d*32+c
// Weight addresses wave-uniform (readfirstlane) -> scalar broadcast loads.
// Intermediates in LDS, odd strides (65/33) -> <=2-way aliasing (free).

template<int LEN>
__device__ __forceinline__ void v2_seg(const float* a, int d, int cb,
    const float* __restrict__ W2v, float* V2, int ln)
{
    cb = __builtin_amdgcn_readfirstlane(cb);
    d  = __builtin_amdgcn_readfirstlane(d);
    const float is32 = 0.17677669529663688f;
    float na[16], nb[16];
    const float4* pa = (const float4*)(a + 32 + 16*d);
    const float4* pb = (const float4*)(a + 80 + 16*d);
#pragma unroll
    for (int q = 0; q < 4; q++) { ((float4*)na)[q] = pa[q]; ((float4*)nb)[q] = pb[q]; }
    float tacc[LEN];
#pragma unroll
    for (int c = 0; c < LEN; c++) tacc[c] = 0.f;
#pragma unroll
    for (int f = 0; f < 16; f++) {
        float fa = na[f], fb = nb[f];
#pragma unroll
        for (int c = 0; c < LEN; c++)
            tacc[c] += fa * W2v[f*32 + cb + c] + fb * W2v[(16+f)*32 + cb + c];
    }
    float* row = V2 + (d*64 + ln) * 33 + cb;
#pragma unroll
    for (int c = 0; c < LEN; c++) row[c] = tacc[c] * is32;
}

template<int LEN>
__device__ __forceinline__ void v3_seg(float* o, int d, int cb,
    const float* __restrict__ W3v, const float* V2, int ln)
{
    cb = __builtin_amdgcn_readfirstlane(cb);
    d  = __builtin_amdgcn_readfirstlane(d);
    const float is32 = 0.17677669529663688f;
    float tacc[LEN];
#pragma unroll
    for (int c = 0; c < LEN; c++) tacc[c] = 0.f;
    const float* row = V2 + (d*64 + ln) * 33;
#pragma unroll
    for (int k = 0; k < 32; k++) {
        float vk = row[k];
#pragma unroll
        for (int c = 0; c < LEN; c++) tacc[c] += vk * W3v[k*32 + cb + c];
    }
#pragma unroll
    for (int c = 0; c < LEN; c++) o[64 + (cb+c)*3 + d] = tacc[c] * is32;
}

__global__ __launch_bounds__(512, 4) void out_kernel(
    const float* __restrict__ acc,      // (N,128) planar
    const float* __restrict__ W2s,      // (32,64)
    const float* __restrict__ W2v,      // (32,32)
    const float* __restrict__ W3s,      // (64,64)
    const float* __restrict__ W3v,      // (32,32)
    float* __restrict__ out)            // (N,160)
{
    __shared__ float S2[64*65];   // S2[ln*65 + c], c<64
    __shared__ float V2[3*64*33]; // V2[(d*64+ln)*33 + c], c<32
    int t = threadIdx.x;
    int w = t >> 6, ln = t & 63;
    int node = blockIdx.x * 64 + ln;
    const float* a = acc + (size_t)node * 128;
    float* o = out + (size_t)node * 160;
    const float is32 = 0.17677669529663688f;

    if (w < 4) {
        int cb = __builtin_amdgcn_readfirstlane(w * 16);
        float n0r[32];
#pragma unroll
        for (int q = 0; q < 8; q++) ((float4*)n0r)[q] = ((const float4*)a)[q];
        float tacc[16];
#pragma unroll
        for (int c = 0; c < 16; c++) tacc[c] = 0.f;
#pragma unroll
        for (int k = 0; k < 32; k++) {
            float nk = n0r[k];
#pragma unroll
            for (int c = 0; c < 16; c++) tacc[c] += nk * W2s[k*64 + cb + c];
        }
        float* row = S2 + ln*65 + cb;
#pragma unroll
        for (int c = 0; c < 16; c++) row[c] = sspf(tacc[c] * is32);
    } else if (w == 4) {
        v2_seg<24>(a, 0, 0,  W2v, V2, ln);
    } else if (w == 5) {
        v2_seg<8> (a, 0, 24, W2v, V2, ln);
        v2_seg<16>(a, 1, 0,  W2v, V2, ln);
    } else if (w == 6) {
        v2_seg<16>(a, 1, 16, W2v, V2, ln);
        v2_seg<8> (a, 2, 0,  W2v, V2, ln);
    } else {
        v2_seg<24>(a, 2, 8,  W2v, V2, ln);
    }
    __syncthreads();
    if (w < 4) {
        int cb = __builtin_amdgcn_readfirstlane(w * 16);
        float tacc[16];
#pragma unroll
        for (int c = 0; c < 16; c++) tacc[c] = 0.f;
        const float* row = S2 + ln*65;
#pragma unroll
        for (int k = 0; k < 64; k++) {
            float sk = row[k];
#pragma unroll
            for (int c = 0; c < 16; c++) tacc[c] += sk * W3s[k*64 + cb + c];
        }
#pragma unroll
        for (int q = 0; q < 4; q++) {
            float4 r = {tacc[q*4+0]*0.125f, tacc[q*4+1]*0.125f,
                        tacc[q*4+2]*0.125f, tacc[q*4+3]*0.125f};
            ((float4*)(o + cb))[q] = r;
        }
    } else if (w == 4) {
        v3_seg<24>(o, 0, 0,  W3v, V2, ln);
    } else if (w == 5) {
        v3_seg<8> (o, 0, 24, W3v, V2, ln);
        v3_seg<16>(o, 1, 0,  W3v, V2, ln);
    } else if (w == 6) {
        v3_seg<16>(o, 1, 16, W3v, V2, ln);
        v3_seg<8> (o, 2, 0,  W3v, V2, ln);
    } else {
        v3_seg<24>(o, 2, 8,  W3v, V2, ln);
    }
}

extern "C" void kernel_launch(void* const* d_in, const int* in_sizes, int n_in,
                              void* d_out, int out_size, void* d_ws, size_t ws_size,
                              hipStream_t stream) {
    const float* x     = (const float*)d_in[0];
    const float* f_ij  = (const float*)d_in[1];
    const float* rcut  = (const float*)d_in[2];
    const float* Yr    = (const float*)d_in[3];
    const float* W1s   = (const float*)d_in[4];
    const float* W1v   = (const float*)d_in[5];
    const float* mW1   = (const float*)d_in[6];
    const float* mb1   = (const float*)d_in[7];
    const float* mW2   = (const float*)d_in[8];
    const float* mb2   = (const float*)d_in[9];
    const float* W2s   = (const float*)d_in[10];
    const float* W2v   = (const float*)d_in[11];
    const float* W3s   = (const float*)d_in[12];
    const float* W3v   = (const float*)d_in[13];
    const int*   idx_i = (const int*)d_in[14];
    const int*   idx_j = (const int*)d_in[15];
    float* out = (float*)d_out;

    // workspace layout (floats)
    float* fws   = (float*)d_ws;
    float* embed = fws;                                  // N*64
    float* acc   = embed + (size_t)NN * 64;              // N*128
    int* ibase   = (int*)(acc + (size_t)NN * 128);
    int* counts  = ibase;                                // N
    int* start   = counts + NN;                          // N+1
    int* rank    = start + NN + 1;                       // E
    int* order   = rank + NE;                            // N
    int* eorder  = order + NN;                           // E

    hipMemsetAsync(counts, 0, (size_t)NN * sizeof(int), stream);
    hist_kernel<<<NE/256, 256, 0, stream>>>(idx_i, counts, rank);
    scan_kernel<<<1, 1024, 0, stream>>>(counts, start, order);
    eorder_kernel<<<NE/256, 256, 0, stream>>>(idx_i, start, rank, eorder);
    embed_kernel<<<NN/256, 256, 0, stream>>>(x, W1s, W1v, embed);
    nodeagg_kernel<<<(NN*16)/256, 256, 0, stream>>>(embed, f_ij, rcut, Yr, idx_j,
                                                    start, order, eorder,
                                                    mW1, mb1, mW2, mb2, acc);
    out_kernel<<<NN/64, 512, 0, stream>>>(acc, W2s, W2v, W3s, W3v, out);
}

// Round 10
// 399.139 us; speedup vs baseline: 1.4025x; 1.4025x over previous
//
#include <hip/hip_runtime.h>
#include <math.h>

#define NN 32768
#define NE 524288
#define RSTR 32      // record stride in floats (128 B, cache-line aligned)
#define SREC_STR 36  // LDS record stride (floats)

// overflow-safe softplus(x) - ln2 using HW exp2/log2 (v_exp_f32 / v_log_f32)
__device__ __forceinline__ float sspf(float x) {
    const float INVLN2 = 1.4426950408889634f;
    const float LN2    = 0.69314718055994530942f;
    float t = __builtin_amdgcn_exp2f(-fabsf(x) * INVLN2);
    return fmaxf(x, 0.0f) + LN2 * __builtin_amdgcn_logf(1.0f + t) - LN2;
}

// ---------------- CSR build + L3 prefetch ----------------
// rank[e] = arrival order of edge e within its segment (atomic return).
// Also streams f_ij/Yr/rcut sequentially so the (memory-side) Infinity
// Cache holds them when pack does its slot-ordered RANDOM reads.
__global__ __launch_bounds__(256) void hist_kernel(
    const int* __restrict__ idx_i, int* __restrict__ counts, int* __restrict__ rank,
    const float* __restrict__ f_ij, const float* __restrict__ Yr,
    const float* __restrict__ rcut)
{
    int e = blockIdx.x * 256 + threadIdx.x;
    rank[e] = atomicAdd(&counts[idx_i[e]], 1);
    const float4* fr = (const float4*)(f_ij + (size_t)e * 32);
    float s = 0.f;
#pragma unroll
    for (int q = 0; q < 8; q++) { float4 v = fr[q]; s += v.x + v.y + v.z + v.w; }
    float4 y = ((const float4*)Yr)[e];
    s += y.x + rcut[e];
    asm volatile("" :: "v"(s));   // keep prefetch loads alive (no DCE)
}

// single block, 1024 threads, 32 counts each; writes start[0..NN] and a
// degree-sorted (descending) node order for nodeagg load balance.
__global__ __launch_bounds__(1024) void scan_kernel(
    const int* __restrict__ counts, int* __restrict__ start, int* __restrict__ order)
{
    __shared__ int tmp[1024];
    __shared__ int bins[64];
    __shared__ int bcur[64];
    int tid = threadIdx.x;
    int base = tid * 32;
    int cnt[32];
    int local[32];
    int sum = 0;
    const int4* c4 = (const int4*)(counts + base);
#pragma unroll
    for (int q = 0; q < 8; q++) {
        int4 v = c4[q];
        cnt[q*4+0] = v.x; cnt[q*4+1] = v.y; cnt[q*4+2] = v.z; cnt[q*4+3] = v.w;
        local[q*4+0] = sum; sum += v.x;
        local[q*4+1] = sum; sum += v.y;
        local[q*4+2] = sum; sum += v.z;
        local[q*4+3] = sum; sum += v.w;
    }
    tmp[tid] = sum;
    __syncthreads();
    for (int off = 1; off < 1024; off <<= 1) {
        int v = 0;
        if (tid >= off) v = tmp[tid - off];
        __syncthreads();
        if (tid >= off) tmp[tid] += v;
        __syncthreads();
    }
    int excl = tmp[tid] - sum;
#pragma unroll
    for (int k = 0; k < 32; k++) {
        start[base + k] = excl + local[k];
    }
    if (tid == 1023) start[NN] = tmp[1023];

    // ---- descending-degree counting sort -> order[] ----
    if (tid < 64) bins[tid] = 0;
    __syncthreads();
#pragma unroll
    for (int k = 0; k < 32; k++) {
        int d = cnt[k] > 63 ? 63 : cnt[k];
        atomicAdd(&bins[63 - d], 1);
    }
    __syncthreads();
    if (tid == 0) {
        int run = 0;
        for (int b = 0; b < 64; b++) { int c = bins[b]; bcur[b] = run; run += c; }
    }
    __syncthreads();
#pragma unroll
    for (int k = 0; k < 32; k++) {
        int d = cnt[k] > 63 ? 63 : cnt[k];
        int pos = atomicAdd(&bcur[63 - d], 1);
        order[pos] = base + k;
    }
}

// ---------------- eorder: CSR slot -> edge id (4B scatter, L2-absorbed) ----
__global__ __launch_bounds__(256) void eorder_kernel(
    const int* __restrict__ idx_i, const int* __restrict__ start,
    const int* __restrict__ rank, int* __restrict__ eorder)
{
    int e = blockIdx.x * 256 + threadIdx.x;
    eorder[start[idx_i[e]] + rank[e]] = e;
}

// ---------------- pack: fused fill + filter-MLP-layer-1, SLOT-ordered ----
// Thread owns CSR slot s; e = eorder[s]. Input reads are random-line but hit
// the L3 (hist pre-warmed). Record written AT s -> epack writes are fully
// sequential streaming (2-phase LDS staging; each store instruction emits
// 4 KB contiguous). nodeagg reads epack sequentially, identical accumulation
// order to the R7 CSR-scatter variant.
__global__ __launch_bounds__(256) void pack_kernel(
    const float* __restrict__ f_ij,     // (E,32)
    const float* __restrict__ rcut_ij,  // (E,)
    const float* __restrict__ Yr,       // (E,4)
    const int*   __restrict__ idx_j,
    const int*   __restrict__ eorder,   // (E,) CSR slot -> edge id
    const float* __restrict__ mW1,      // (32,16)
    const float* __restrict__ mb1,      // (16,)
    float* __restrict__ epack)
{
    __shared__ float sW1[512];
    __shared__ float sb1[16];
    __shared__ float srec[128 * SREC_STR];  // 18 KB
    int t = threadIdx.x;
    for (int k = t; k < 512; k += 256) sW1[k] = mW1[k];
    if (t < 16) sb1[t] = mb1[t];
    __syncthreads();

    int s = blockIdx.x * 256 + t;
    int e = eorder[s];

    float h[16];
#pragma unroll
    for (int f = 0; f < 16; f++) h[f] = sb1[f];
    const float4* frow = (const float4*)(f_ij + (size_t)e * 32);
#pragma unroll
    for (int rq = 0; rq < 8; rq++) {
        float4 fv = frow[rq];
        int r = rq * 4;
#pragma unroll
        for (int f = 0; f < 16; f++)
            h[f] += fv.x * sW1[(r+0)*16+f] + fv.y * sW1[(r+1)*16+f]
                  + fv.z * sW1[(r+2)*16+f] + fv.w * sW1[(r+3)*16+f];
    }
    float rc = rcut_ij[e];
#pragma unroll
    for (int f = 0; f < 16; f++) h[f] = sspf(h[f]) * rc;

    int j = idx_j[e];
    float4 y = ((const float4*)Yr)[e];

    size_t base = (size_t)blockIdx.x * 256;
#pragma unroll 1
    for (int p = 0; p < 2; p++) {
        if ((t >> 7) == p) {
            int r = t & 127;
            float4* rp4 = (float4*)(srec + r * SREC_STR);
#pragma unroll
            for (int q = 0; q < 4; q++) rp4[q] = ((float4*)h)[q];
            rp4[4] = y;
            float4 tail; tail.x = rc; tail.y = __int_as_float(j);
            tail.z = 0.f; tail.w = 0.f;
            rp4[5] = tail;
            float4 z; z.x = 0.f; z.y = 0.f; z.z = 0.f; z.w = 0.f;
            rp4[6] = z;
            rp4[7] = z;
        }
        __syncthreads();
        // 128 records x 8 quarters = 1024 float4s / 256 threads = 4 each;
        // destination is CONTIGUOUS: slots base+p*128 .. base+p*128+127.
#pragma unroll
        for (int g = 0; g < 4; g++) {
            int idx = g * 256 + t;
            int r = idx >> 3;
            int qi = idx & 7;
            float4 v = ((const float4*)(srec + r * SREC_STR))[qi];
            ((float4*)(epack + (base + p * 128 + r) * RSTR))[qi] = v;
        }
        __syncthreads();   // srec reuse safe for next phase
    }
}

// ---------------- node embedding ----------------
// interleaved output layout: embed[n*64 + f*4 + {0,1,2,3}] = {s1, v1x, v1y, v1z}
// so nodeagg fetches one float4 per (edge, lane).
// Staging loops are CHUNKED (#pragma unroll 1) to cap live registers.
__global__ __launch_bounds__(256) void embed_kernel(
    const float* __restrict__ x,
    const float* __restrict__ W1s,   // (64,16)
    const float* __restrict__ W1v,   // (32,16)
    float* __restrict__ embed)
{
    __shared__ float sWs[1024];
    __shared__ float sWv[512];
    int t = threadIdx.x;
    for (int k = t; k < 1024; k += 256) sWs[k] = W1s[k];
    for (int k = t; k < 512;  k += 256) sWv[k] = W1v[k];
    __syncthreads();

    int n = blockIdx.x * 256 + t;
    const float* xr = x + (size_t)n * 160;

    float s1[16];
#pragma unroll
    for (int f = 0; f < 16; f++) s1[f] = 0.f;
#pragma unroll 1
    for (int cc = 0; cc < 4; cc++) {
        float4 sv[4];
#pragma unroll
        for (int q = 0; q < 4; q++) sv[q] = ((const float4*)xr)[cc*4 + q];
#pragma unroll
        for (int q = 0; q < 4; q++) {
            int c = (cc*4 + q) * 4;
#pragma unroll
            for (int f = 0; f < 16; f++) {
                s1[f] += sv[q].x * sWs[(c+0)*16+f] + sv[q].y * sWs[(c+1)*16+f]
                       + sv[q].z * sWs[(c+2)*16+f] + sv[q].w * sWs[(c+3)*16+f];
            }
        }
    }

    float v1[48];
#pragma unroll
    for (int k = 0; k < 48; k++) v1[k] = 0.f;
    // 96 vector components = 4 chunks x 24 (= 8 columns x 3 dims each chunk)
#pragma unroll 1
    for (int cc = 0; cc < 4; cc++) {
        float4 vv[6];
#pragma unroll
        for (int q = 0; q < 6; q++) vv[q] = ((const float4*)(xr + 64))[cc*6 + q];
#pragma unroll
        for (int q = 0; q < 6; q++) {
            float vals[4] = {vv[q].x, vv[q].y, vv[q].z, vv[q].w};
#pragma unroll
            for (int u = 0; u < 4; u++) {
                int ml = q * 4 + u;         // 0..23, static
                int c = cc * 8 + ml / 3;    // runtime base + static
                int d = ml % 3;             // static
                float val = vals[u];
#pragma unroll
                for (int f = 0; f < 16; f++)
                    v1[f*3+d] += val * sWv[c*16+f];
            }
        }
    }

    float ob[64];
    const float is32 = 0.17677669529663688f;
#pragma unroll
    for (int f = 0; f < 16; f++) {
        ob[f*4+0] = s1[f] * 0.125f;
        ob[f*4+1] = v1[f*3+0] * is32;
        ob[f*4+2] = v1[f*3+1] * is32;
        ob[f*4+3] = v1[f*3+2] * is32;
    }

    float4* eo = (float4*)(embed + (size_t)n * 64);
#pragma unroll
    for (int q = 0; q < 16; q++) eo[q] = ((float4*)ob)[q];
}

// ---------------- node-centric aggregation ----------------
// 16 threads per node (4 nodes per wave), thread owns a single f.
// __launch_bounds__(256,4) -> 128-VGPR budget so the 64 per-thread weights
// live in REGISTERS. Nodes processed in descending-degree order (order[]).
// epack is in CSR order -> sequential record reads.
__global__ __launch_bounds__(256, 4) void nodeagg_kernel(
    const float* __restrict__ embed,   // (N,64) interleaved (f*4+{s,x,y,z})
    const float* __restrict__ epack,   // (E,RSTR) CSR-ordered records
    const int*   __restrict__ start,   // (N+1,)
    const int*   __restrict__ order,   // (N,) degree-sorted node ids
    const float* __restrict__ mW2,     // (16,96)
    const float* __restrict__ mb2,     // (96,)
    float* __restrict__ acc)           // (N,128) planar
{
    int t = threadIdx.x;
    int gid = blockIdx.x * 256 + t;
    int node = order[gid >> 4];
    int f = gid & 15;

    float wga[16], wgb[16], wgc[16], wgd[16];
#pragma unroll
    for (int k = 0; k < 16; k++) {
        wga[k] = mW2[k*96 + f];
        wgb[k] = mW2[k*96 + 16 + f];
        wgc[k] = mW2[k*96 + 32 + f];
        wgd[k] = mW2[k*96 + 48 + f];
    }
    float b0a = mb2[f], b0b = mb2[16+f], b1a = mb2[32+f], b1b = mb2[48+f];

    float aa = 0.f, ab = 0.f;
    float A1a0 = 0.f, A1a1 = 0.f, A1a2 = 0.f;
    float A1b0 = 0.f, A1b1 = 0.f, A1b2 = 0.f;

    int s0 = start[node];
    int s1 = start[node+1];

    for (int q = s0; q < s1; q++) {
        const float4* r4 = (const float4*)(epack + (size_t)q * RSTR);
        float4 h0 = r4[0], h1 = r4[1], h2 = r4[2], h3 = r4[3];
        float4 y  = r4[4], tl = r4[5];
        int j = __float_as_int(tl.y);
        float4 e4 = ((const float4*)(embed + (size_t)j * 64))[f];
        float rc = tl.x;

        float w0a = rc*b0a, w0b = rc*b0b, w1a = rc*b1a, w1b = rc*b1b;
        w0a += h0.x*wga[0]  + h0.y*wga[1]  + h0.z*wga[2]  + h0.w*wga[3]
             + h1.x*wga[4]  + h1.y*wga[5]  + h1.z*wga[6]  + h1.w*wga[7]
             + h2.x*wga[8]  + h2.y*wga[9]  + h2.z*wga[10] + h2.w*wga[11]
             + h3.x*wga[12] + h3.y*wga[13] + h3.z*wga[14] + h3.w*wga[15];
        w0b += h0.x*wgb[0]  + h0.y*wgb[1]  + h0.z*wgb[2]  + h0.w*wgb[3]
             + h1.x*wgb[4]  + h1.y*wgb[5]  + h1.z*wgb[6]  + h1.w*wgb[7]
             + h2.x*wgb[8]  + h2.y*wgb[9]  + h2.z*wgb[10] + h2.w*wgb[11]
             + h3.x*wgb[12] + h3.y*wgb[13] + h3.z*wgb[14] + h3.w*wgb[15];
        w1a += h0.x*wgc[0]  + h0.y*wgc[1]  + h0.z*wgc[2]  + h0.w*wgc[3]
             + h1.x*wgc[4]  + h1.y*wgc[5]  + h1.z*wgc[6]  + h1.w*wgc[7]
             + h2.x*wgc[8]  + h2.y*wgc[9]  + h2.z*wgc[10] + h2.w*wgc[11]
             + h3.x*wgc[12] + h3.y*wgc[13] + h3.z*wgc[14] + h3.w*wgc[15];
        w1b += h0.x*wgd[0]  + h0.y*wgd[1]  + h0.z*wgd[2]  + h0.w*wgd[3]
             + h1.x*wgd[4]  + h1.y*wgd[5]  + h1.z*wgd[6]  + h1.w*wgd[7]
             + h2.x*wgd[8]  + h2.y*wgd[9]  + h2.z*wgd[10] + h2.w*wgd[11]
             + h3.x*wgd[12] + h3.y*wgd[13] + h3.z*wgd[14] + h3.w*wgd[15];

        float sj = e4.x, vx = e4.y, vy = e4.z, vz = e4.w;
        aa += sj * y.x * w0a;
        ab += (vx*y.y + vy*y.z + vz*y.w) * w0b;
        float sw = sj * w1a;
        A1a0 += sw * y.y;
        A1a1 += sw * y.z;
        A1a2 += sw * y.w;
        float yw = y.x * w1b;
        A1b0 += vx * yw;
        A1b1 += vy * yw;
        A1b2 += vz * yw;
    }

    const float is3 = 0.5773502691896258f;   // 1/sqrt(3)
    float* o = acc + (size_t)node * 128;
    o[f]       = aa;
    o[16 + f]  = ab * is3;
    o[32 + f]  = A1a0;
    o[48 + f]  = A1a1;
    o[64 + f]  = A1a2;
    o[80 + f]  = A1b0;
    o[96 + f]  = A1b1;
    o[112 + f] = A1b2;
}

// ---------------- node output ----------------
// 64 nodes per block (lane = node), 512 threads = 8 waves (balanced roles):
// waves 0-3: s-chain, 16 cols each (s2 k=32, s3 k=64)
// waves 4-7: v-chain, 24 col-dims each over flattened cd = d*32+c
// Weight addresses wave-uniform (readfirstlane) -> scalar broadcast loads.
// Intermediates in LDS, odd strides (65/33) -> <=2-way aliasing (free).

template<int LEN>
__device__ __forceinline__ void v2_seg(const float* a, int d, int cb,
    const float* __restrict__ W2v, float* V2, int ln)
{
    cb = __builtin_amdgcn_readfirstlane(cb);
    d  = __builtin_amdgcn_readfirstlane(d);
    const float is32 = 0.17677669529663688f;
    float na[16], nb[16];
    const float4* pa = (const float4*)(a + 32 + 16*d);
    const float4* pb = (const float4*)(a + 80 + 16*d);
#pragma unroll
    for (int q = 0; q < 4; q++) { ((float4*)na)[q] = pa[q]; ((float4*)nb)[q] = pb[q]; }
    float tacc[LEN];
#pragma unroll
    for (int c = 0; c < LEN; c++) tacc[c] = 0.f;
#pragma unroll
    for (int f = 0; f < 16; f++) {
        float fa = na[f], fb = nb[f];
#pragma unroll
        for (int c = 0; c < LEN; c++)
            tacc[c] += fa * W2v[f*32 + cb + c] + fb * W2v[(16+f)*32 + cb + c];
    }
    float* row = V2 + (d*64 + ln) * 33 + cb;
#pragma unroll
    for (int c = 0; c < LEN; c++) row[c] = tacc[c] * is32;
}

template<int LEN>
__device__ __forceinline__ void v3_seg(float* o, int d, int cb,
    const float* __restrict__ W3v, const float* V2, int ln)
{
    cb = __builtin_amdgcn_readfirstlane(cb);
    d  = __builtin_amdgcn_readfirstlane(d);
    const float is32 = 0.17677669529663688f;
    float tacc[LEN];
#pragma unroll
    for (int c = 0; c < LEN; c++) tacc[c] = 0.f;
    const float* row = V2 + (d*64 + ln) * 33;
#pragma unroll
    for (int k = 0; k < 32; k++) {
        float vk = row[k];
#pragma unroll
        for (int c = 0; c < LEN; c++) tacc[c] += vk * W3v[k*32 + cb + c];
    }
#pragma unroll
    for (int c = 0; c < LEN; c++) o[64 + (cb+c)*3 + d] = tacc[c] * is32;
}

__global__ __launch_bounds__(512, 4) void out_kernel(
    const float* __restrict__ acc,      // (N,128) planar
    const float* __restrict__ W2s,      // (32,64)
    const float* __restrict__ W2v,      // (32,32)
    const float* __restrict__ W3s,      // (64,64)
    const float* __restrict__ W3v,      // (32,32)
    float* __restrict__ out)            // (N,160)
{
    __shared__ float S2[64*65];   // S2[ln*65 + c], c<64
    __shared__ float V2[3*64*33]; // V2[(d*64+ln)*33 + c], c<32
    int t = threadIdx.x;
    int w = t >> 6, ln = t & 63;
    int node = blockIdx.x * 64 + ln;
    const float* a = acc + (size_t)node * 128;
    float* o = out + (size_t)node * 160;
    const float is32 = 0.17677669529663688f;

    if (w < 4) {
        int cb = __builtin_amdgcn_readfirstlane(w * 16);
        float n0r[32];
#pragma unroll
        for (int q = 0; q < 8; q++) ((float4*)n0r)[q] = ((const float4*)a)[q];
        float tacc[16];
#pragma unroll
        for (int c = 0; c < 16; c++) tacc[c] = 0.f;
#pragma unroll
        for (int k = 0; k < 32; k++) {
            float nk = n0r[k];
#pragma unroll
            for (int c = 0; c < 16; c++) tacc[c] += nk * W2s[k*64 + cb + c];
        }
        float* row = S2 + ln*65 + cb;
#pragma unroll
        for (int c = 0; c < 16; c++) row[c] = sspf(tacc[c] * is32);
    } else if (w == 4) {
        v2_seg<24>(a, 0, 0,  W2v, V2, ln);
    } else if (w == 5) {
        v2_seg<8> (a, 0, 24, W2v, V2, ln);
        v2_seg<16>(a, 1, 0,  W2v, V2, ln);
    } else if (w == 6) {
        v2_seg<16>(a, 1, 16, W2v, V2, ln);
        v2_seg<8> (a, 2, 0,  W2v, V2, ln);
    } else {
        v2_seg<24>(a, 2, 8,  W2v, V2, ln);
    }
    __syncthreads();
    if (w < 4) {
        int cb = __builtin_amdgcn_readfirstlane(w * 16);
        float tacc[16];
#pragma unroll
        for (int c = 0; c < 16; c++) tacc[c] = 0.f;
        const float* row = S2 + ln*65;
#pragma unroll
        for (int k = 0; k < 64; k++) {
            float sk = row[k];
#pragma unroll
            for (int c = 0; c < 16; c++) tacc[c] += sk * W3s[k*64 + cb + c];
        }
#pragma unroll
        for (int q = 0; q < 4; q++) {
            float4 r = {tacc[q*4+0]*0.125f, tacc[q*4+1]*0.125f,
                        tacc[q*4+2]*0.125f, tacc[q*4+3]*0.125f};
            ((float4*)(o + cb))[q] = r;
        }
    } else if (w == 4) {
        v3_seg<24>(o, 0, 0,  W3v, V2, ln);
    } else if (w == 5) {
        v3_seg<8> (o, 0, 24, W3v, V2, ln);
        v3_seg<16>(o, 1, 0,  W3v, V2, ln);
    } else if (w == 6) {
        v3_seg<16>(o, 1, 16, W3v, V2, ln);
        v3_seg<8> (o, 2, 0,  W3v, V2, ln);
    } else {
        v3_seg<24>(o, 2, 8,  W3v, V2, ln);
    }
}

extern "C" void kernel_launch(void* const* d_in, const int* in_sizes, int n_in,
                              void* d_out, int out_size, void* d_ws, size_t ws_size,
                              hipStream_t stream) {
    const float* x     = (const float*)d_in[0];
    const float* f_ij  = (const float*)d_in[1];
    const float* rcut  = (const float*)d_in[2];
    const float* Yr    = (const float*)d_in[3];
    const float* W1s   = (const float*)d_in[4];
    const float* W1v   = (const float*)d_in[5];
    const float* mW1   = (const float*)d_in[6];
    const float* mb1   = (const float*)d_in[7];
    const float* mW2   = (const float*)d_in[8];
    const float* mb2   = (const float*)d_in[9];
    const float* W2s   = (const float*)d_in[10];
    const float* W2v   = (const float*)d_in[11];
    const float* W3s   = (const float*)d_in[12];
    const float* W3v   = (const float*)d_in[13];
    const int*   idx_i = (const int*)d_in[14];
    const int*   idx_j = (const int*)d_in[15];
    float* out = (float*)d_out;

    // workspace layout (floats)
    float* fws   = (float*)d_ws;
    float* embed = fws;                                  // N*64
    float* acc   = embed + (size_t)NN * 64;              // N*128
    float* epack = acc   + (size_t)NN * 128;             // E*RSTR
    int* ibase   = (int*)(epack + (size_t)NE * RSTR);
    int* counts  = ibase;                                // N
    int* start   = counts + NN;                          // N+1
    int* rank    = start + NN + 1;                       // E
    int* order   = rank + NE;                            // N
    int* eorder  = order + NN;                           // E

    hipMemsetAsync(counts, 0, (size_t)NN * sizeof(int), stream);
    hist_kernel<<<NE/256, 256, 0, stream>>>(idx_i, counts, rank, f_ij, Yr, rcut);
    scan_kernel<<<1, 1024, 0, stream>>>(counts, start, order);
    eorder_kernel<<<NE/256, 256, 0, stream>>>(idx_i, start, rank, eorder);
    pack_kernel<<<NE/256, 256, 0, stream>>>(f_ij, rcut, Yr, idx_j, eorder,
                                            mW1, mb1, epack);
    embed_kernel<<<NN/256, 256, 0, stream>>>(x, W1s, W1v, embed);
    nodeagg_kernel<<<(NN*16)/256, 256, 0, stream>>>(embed, epack, start, order,
                                                    mW2, mb2, acc);
    out_kernel<<<NN/64, 512, 0, stream>>>(acc, W2s, W2v, W3s, W3v, out);
}

// Round 11
// 345.814 us; speedup vs baseline: 1.6187x; 1.1542x over previous
//
#include <hip/hip_runtime.h>
#include <math.h>

#define NN 32768
#define NE 524288
#define RSTR 32      // record stride in floats (128 B, cache-line aligned)
#define SREC_STR 36  // LDS record stride (floats)

// overflow-safe softplus(x) - ln2 using HW exp2/log2 (v_exp_f32 / v_log_f32)
__device__ __forceinline__ float sspf(float x) {
    const float INVLN2 = 1.4426950408889634f;
    const float LN2    = 0.69314718055994530942f;
    float t = __builtin_amdgcn_exp2f(-fabsf(x) * INVLN2);
    return fmaxf(x, 0.0f) + LN2 * __builtin_amdgcn_logf(1.0f + t) - LN2;
}

// ---------------- CSR build ----------------
// rank[e] = arrival order of edge e within its segment (atomic return).
__global__ __launch_bounds__(256) void hist_kernel(
    const int* __restrict__ idx_i, int* __restrict__ counts, int* __restrict__ rank)
{
    int e = blockIdx.x * 256 + threadIdx.x;
    rank[e] = atomicAdd(&counts[idx_i[e]], 1);
}

// single block, 1024 threads, 32 counts each; writes start[0..NN] and a
// degree-sorted (descending) node order for nodeagg load balance.
__global__ __launch_bounds__(1024) void scan_kernel(
    const int* __restrict__ counts, int* __restrict__ start, int* __restrict__ order)
{
    __shared__ int tmp[1024];
    __shared__ int bins[64];
    __shared__ int bcur[64];
    int tid = threadIdx.x;
    int base = tid * 32;
    int cnt[32];
    int local[32];
    int sum = 0;
    const int4* c4 = (const int4*)(counts + base);
#pragma unroll
    for (int q = 0; q < 8; q++) {
        int4 v = c4[q];
        cnt[q*4+0] = v.x; cnt[q*4+1] = v.y; cnt[q*4+2] = v.z; cnt[q*4+3] = v.w;
        local[q*4+0] = sum; sum += v.x;
        local[q*4+1] = sum; sum += v.y;
        local[q*4+2] = sum; sum += v.z;
        local[q*4+3] = sum; sum += v.w;
    }
    tmp[tid] = sum;
    __syncthreads();
    for (int off = 1; off < 1024; off <<= 1) {
        int v = 0;
        if (tid >= off) v = tmp[tid - off];
        __syncthreads();
        if (tid >= off) tmp[tid] += v;
        __syncthreads();
    }
    int excl = tmp[tid] - sum;
#pragma unroll
    for (int k = 0; k < 32; k++) {
        start[base + k] = excl + local[k];
    }
    if (tid == 1023) start[NN] = tmp[1023];

    // ---- descending-degree counting sort -> order[] ----
    if (tid < 64) bins[tid] = 0;
    __syncthreads();
#pragma unroll
    for (int k = 0; k < 32; k++) {
        int d = cnt[k] > 63 ? 63 : cnt[k];
        atomicAdd(&bins[63 - d], 1);
    }
    __syncthreads();
    if (tid == 0) {
        int run = 0;
        for (int b = 0; b < 64; b++) { int c = bins[b]; bcur[b] = run; run += c; }
    }
    __syncthreads();
#pragma unroll
    for (int k = 0; k < 32; k++) {
        int d = cnt[k] > 63 ? 63 : cnt[k];
        int pos = atomicAdd(&bcur[63 - d], 1);
        order[pos] = base + k;
    }
}

// ---------------- pack: fused fill + filter-MLP-layer-1 ----------------
// record (32 floats = one 128B line): [0:16)=h*rc, [16:20)=Yr, [20]=rc,
// [21]=j(bits), [22:32)=zero pad.
// TWO-PHASE cooperative scatter: phase p stages 128 records in LDS, then all
// 256 threads emit them as full 128B lines (8 lanes cover the 8 float4
// quarters of one record per store instruction).
__global__ __launch_bounds__(256) void pack_kernel(
    const float* __restrict__ f_ij,     // (E,32)
    const float* __restrict__ rcut_ij,  // (E,)
    const float* __restrict__ Yr,       // (E,4)
    const int*   __restrict__ idx_i,
    const int*   __restrict__ idx_j,
    const float* __restrict__ mW1,      // (32,16)
    const float* __restrict__ mb1,      // (16,)
    const int*   __restrict__ start,    // (N+1,)
    const int*   __restrict__ rank,     // (E,)
    float* __restrict__ epack)
{
    __shared__ float sW1[512];
    __shared__ float sb1[16];
    __shared__ float srec[128 * SREC_STR];  // 18 KB
    __shared__ int   sslot[128];
    int t = threadIdx.x;
    for (int k = t; k < 512; k += 256) sW1[k] = mW1[k];
    if (t < 16) sb1[t] = mb1[t];
    __syncthreads();

    int e = blockIdx.x * 256 + t;
    float h[16];
#pragma unroll
    for (int f = 0; f < 16; f++) h[f] = sb1[f];
    const float4* frow = (const float4*)(f_ij + (size_t)e * 32);
#pragma unroll
    for (int rq = 0; rq < 8; rq++) {
        float4 fv = frow[rq];
        int r = rq * 4;
#pragma unroll
        for (int f = 0; f < 16; f++)
            h[f] += fv.x * sW1[(r+0)*16+f] + fv.y * sW1[(r+1)*16+f]
                  + fv.z * sW1[(r+2)*16+f] + fv.w * sW1[(r+3)*16+f];
    }
    float rc = rcut_ij[e];
#pragma unroll
    for (int f = 0; f < 16; f++) h[f] = sspf(h[f]) * rc;

    int i = idx_i[e];
    int j = idx_j[e];
    float4 y = ((const float4*)Yr)[e];
    int slot = start[i] + rank[e];

#pragma unroll 1
    for (int p = 0; p < 2; p++) {
        if ((t >> 7) == p) {
            int r = t & 127;
            float4* rp4 = (float4*)(srec + r * SREC_STR);
#pragma unroll
            for (int q = 0; q < 4; q++) rp4[q] = ((float4*)h)[q];
            rp4[4] = y;
            float4 tail; tail.x = rc; tail.y = __int_as_float(j);
            tail.z = 0.f; tail.w = 0.f;
            rp4[5] = tail;
            float4 z; z.x = 0.f; z.y = 0.f; z.z = 0.f; z.w = 0.f;
            rp4[6] = z;
            rp4[7] = z;
            sslot[r] = slot;
        }
        __syncthreads();
        // 128 records x 8 quarters = 1024 float4s / 256 threads = 4 each
#pragma unroll
        for (int g = 0; g < 4; g++) {
            int idx = g * 256 + t;
            int r = idx >> 3;
            int qi = idx & 7;
            int s = sslot[r];
            float4 v = ((const float4*)(srec + r * SREC_STR))[qi];
            ((float4*)(epack + (size_t)s * RSTR))[qi] = v;
        }
        __syncthreads();   // srec reuse safe for next phase
    }
}

// ---------------- node embedding ----------------
// interleaved output layout: embed[n*64 + f*4 + {0,1,2,3}] = {s1, v1x, v1y, v1z}
// so nodeagg fetches one float4 per (edge, lane).
// Staging loops are CHUNKED (#pragma unroll 1) to cap live registers.
__global__ __launch_bounds__(256) void embed_kernel(
    const float* __restrict__ x,
    const float* __restrict__ W1s,   // (64,16)
    const float* __restrict__ W1v,   // (32,16)
    float* __restrict__ embed)
{
    __shared__ float sWs[1024];
    __shared__ float sWv[512];
    int t = threadIdx.x;
    for (int k = t; k < 1024; k += 256) sWs[k] = W1s[k];
    for (int k = t; k < 512;  k += 256) sWv[k] = W1v[k];
    __syncthreads();

    int n = blockIdx.x * 256 + t;
    const float* xr = x + (size_t)n * 160;

    float s1[16];
#pragma unroll
    for (int f = 0; f < 16; f++) s1[f] = 0.f;
#pragma unroll 1
    for (int cc = 0; cc < 4; cc++) {
        float4 sv[4];
#pragma unroll
        for (int q = 0; q < 4; q++) sv[q] = ((const float4*)xr)[cc*4 + q];
#pragma unroll
        for (int q = 0; q < 4; q++) {
            int c = (cc*4 + q) * 4;
#pragma unroll
            for (int f = 0; f < 16; f++) {
                s1[f] += sv[q].x * sWs[(c+0)*16+f] + sv[q].y * sWs[(c+1)*16+f]
                       + sv[q].z * sWs[(c+2)*16+f] + sv[q].w * sWs[(c+3)*16+f];
            }
        }
    }

    float v1[48];
#pragma unroll
    for (int k = 0; k < 48; k++) v1[k] = 0.f;
    // 96 vector components = 4 chunks x 24 (= 8 columns x 3 dims each chunk)
#pragma unroll 1
    for (int cc = 0; cc < 4; cc++) {
        float4 vv[6];
#pragma unroll
        for (int q = 0; q < 6; q++) vv[q] = ((const float4*)(xr + 64))[cc*6 + q];
#pragma unroll
        for (int q = 0; q < 6; q++) {
            float vals[4] = {vv[q].x, vv[q].y, vv[q].z, vv[q].w};
#pragma unroll
            for (int u = 0; u < 4; u++) {
                int ml = q * 4 + u;         // 0..23, static
                int c = cc * 8 + ml / 3;    // runtime base + static
                int d = ml % 3;             // static
                float val = vals[u];
#pragma unroll
                for (int f = 0; f < 16; f++)
                    v1[f*3+d] += val * sWv[c*16+f];
            }
        }
    }

    float ob[64];
    const float is32 = 0.17677669529663688f;
#pragma unroll
    for (int f = 0; f < 16; f++) {
        ob[f*4+0] = s1[f] * 0.125f;
        ob[f*4+1] = v1[f*3+0] * is32;
        ob[f*4+2] = v1[f*3+1] * is32;
        ob[f*4+3] = v1[f*3+2] * is32;
    }

    float4* eo = (float4*)(embed + (size_t)n * 64);
#pragma unroll
    for (int q = 0; q < 16; q++) eo[q] = ((float4*)ob)[q];
}

// ---------------- node-centric aggregation ----------------
// 16 threads per node (4 nodes per wave), thread owns a single f.
// __launch_bounds__(256,4) -> 128-VGPR budget so the 64 per-thread weights
// live in REGISTERS. Nodes processed in descending-degree order (order[]).
// epack is in CSR order -> sequential record reads.
__global__ __launch_bounds__(256, 4) void nodeagg_kernel(
    const float* __restrict__ embed,   // (N,64) interleaved (f*4+{s,x,y,z})
    const float* __restrict__ epack,   // (E,RSTR) CSR-ordered records
    const int*   __restrict__ start,   // (N+1,)
    const int*   __restrict__ order,   // (N,) degree-sorted node ids
    const float* __restrict__ mW2,     // (16,96)
    const float* __restrict__ mb2,     // (96,)
    float* __restrict__ acc)           // (N,128) planar
{
    int t = threadIdx.x;
    int gid = blockIdx.x * 256 + t;
    int node = order[gid >> 4];
    int f = gid & 15;

    float wga[16], wgb[16], wgc[16], wgd[16];
#pragma unroll
    for (int k = 0; k < 16; k++) {
        wga[k] = mW2[k*96 + f];
        wgb[k] = mW2[k*96 + 16 + f];
        wgc[k] = mW2[k*96 + 32 + f];
        wgd[k] = mW2[k*96 + 48 + f];
    }
    float b0a = mb2[f], b0b = mb2[16+f], b1a = mb2[32+f], b1b = mb2[48+f];

    float aa = 0.f, ab = 0.f;
    float A1a0 = 0.f, A1a1 = 0.f, A1a2 = 0.f;
    float A1b0 = 0.f, A1b1 = 0.f, A1b2 = 0.f;

    int s0 = start[node];
    int s1 = start[node+1];

    for (int q = s0; q < s1; q++) {
        const float4* r4 = (const float4*)(epack + (size_t)q * RSTR);
        float4 h0 = r4[0], h1 = r4[1], h2 = r4[2], h3 = r4[3];
        float4 y  = r4[4], tl = r4[5];
        int j = __float_as_int(tl.y);
        float4 e4 = ((const float4*)(embed + (size_t)j * 64))[f];
        float rc = tl.x;

        float w0a = rc*b0a, w0b = rc*b0b, w1a = rc*b1a, w1b = rc*b1b;
        w0a += h0.x*wga[0]  + h0.y*wga[1]  + h0.z*wga[2]  + h0.w*wga[3]
             + h1.x*wga[4]  + h1.y*wga[5]  + h1.z*wga[6]  + h1.w*wga[7]
             + h2.x*wga[8]  + h2.y*wga[9]  + h2.z*wga[10] + h2.w*wga[11]
             + h3.x*wga[12] + h3.y*wga[13] + h3.z*wga[14] + h3.w*wga[15];
        w0b += h0.x*wgb[0]  + h0.y*wgb[1]  + h0.z*wgb[2]  + h0.w*wgb[3]
             + h1.x*wgb[4]  + h1.y*wgb[5]  + h1.z*wgb[6]  + h1.w*wgb[7]
             + h2.x*wgb[8]  + h2.y*wgb[9]  + h2.z*wgb[10] + h2.w*wgb[11]
             + h3.x*wgb[12] + h3.y*wgb[13] + h3.z*wgb[14] + h3.w*wgb[15];
        w1a += h0.x*wgc[0]  + h0.y*wgc[1]  + h0.z*wgc[2]  + h0.w*wgc[3]
             + h1.x*wgc[4]  + h1.y*wgc[5]  + h1.z*wgc[6]  + h1.w*wgc[7]
             + h2.x*wgc[8]  + h2.y*wgc[9]  + h2.z*wgc[10] + h2.w*wgc[11]
             + h3.x*wgc[12] + h3.y*wgc[13] + h3.z*wgc[14] + h3.w*wgc[15];
        w1b += h0.x*wgd[0]  + h0.y*wgd[1]  + h0.z*wgd[2]  + h0.w*wgd[3]
             + h1.x*wgd[4]  + h1.y*wgd[5]  + h1.z*wgd[6]  + h1.w*wgd[7]
             + h2.x*wgd[8]  + h2.y*wgd[9]  + h2.z*wgd[10] + h2.w*wgd[11]
             + h3.x*wgd[12] + h3.y*wgd[13] + h3.z*wgd[14] + h3.w*wgd[15];

        float sj = e4.x, vx = e4.y, vy = e4.z, vz = e4.w;
        aa += sj * y.x * w0a;
        ab += (vx*y.y + vy*y.z + vz*y.w) * w0b;
        float sw = sj * w1a;
        A1a0 += sw * y.y;
        A1a1 += sw * y.z;
        A1a2 += sw * y.w;
        float yw = y.x * w1b;
        A1b0 += vx * yw;
        A1b1 += vy * yw;
        A1b2 += vz * yw;
    }

    const float is3 = 0.5773502691896258f;   // 1/sqrt(3)
    float* o = acc + (size_t)node * 128;
    o[f]       = aa;
    o[16 + f]  = ab * is3;
    o[32 + f]  = A1a0;
    o[48 + f]  = A1a1;
    o[64 + f]  = A1a2;
    o[80 + f]  = A1b0;
    o[96 + f]  = A1b1;
    o[112 + f] = A1b2;
}

// ---------------- node output ----------------
// 32 nodes per block, 320 threads = 5 waves, all roles d-aligned & uniform
// (every segment LEN=16 -> zero intra-wave divergence):
//   wave 0: s-chain cols h*16      (h = half-wave = (t>>5)&1)
//   wave 1: s-chain cols 32+h*16
//   wave 2/3/4: v-chain d=0/1/2, cols h*16
// Grid = NN/32 = 1024 blocks; LDS ~21 KB -> ~6 blocks/CU = 30 waves (94% cap)
// vs previous 512-block/2-per-CU hard cap (41% occupancy, 96 us latency-bound).

__global__ __launch_bounds__(320) void out_kernel(
    const float* __restrict__ acc,      // (N,128) planar
    const float* __restrict__ W2s,      // (32,64)
    const float* __restrict__ W2v,      // (32,32)
    const float* __restrict__ W3s,      // (64,64)
    const float* __restrict__ W3v,      // (32,32)
    float* __restrict__ out)            // (N,160)
{
    __shared__ float S2[32*65];   // S2[ln*65 + c], c<64
    __shared__ float V2[3*32*33]; // V2[(d*32+ln)*33 + c], c<32
    int t = threadIdx.x;
    int w = t >> 6;               // wave 0..4 (wave-uniform)
    int h = (t >> 5) & 1;         // half-wave
    int ln = t & 31;              // node within block
    int node = blockIdx.x * 32 + ln;
    const float* a = acc + (size_t)node * 128;
    float* o = out + (size_t)node * 160;
    const float is32 = 0.17677669529663688f;

    if (w < 2) {
        int cb = w * 32 + h * 16;
        float n0r[32];
#pragma unroll
        for (int q = 0; q < 8; q++) ((float4*)n0r)[q] = ((const float4*)a)[q];
        float tacc[16];
#pragma unroll
        for (int c = 0; c < 16; c++) tacc[c] = 0.f;
#pragma unroll
        for (int k = 0; k < 32; k++) {
            float nk = n0r[k];
#pragma unroll
            for (int c = 0; c < 16; c++) tacc[c] += nk * W2s[k*64 + cb + c];
        }
        float* row = S2 + ln*65 + cb;
#pragma unroll
        for (int c = 0; c < 16; c++) row[c] = sspf(tacc[c] * is32);
    } else {
        int d = w - 2;
        int cb = h * 16;
        float na[16], nb[16];
        const float4* pa = (const float4*)(a + 32 + 16*d);
        const float4* pb = (const float4*)(a + 80 + 16*d);
#pragma unroll
        for (int q = 0; q < 4; q++) { ((float4*)na)[q] = pa[q]; ((float4*)nb)[q] = pb[q]; }
        float tacc[16];
#pragma unroll
        for (int c = 0; c < 16; c++) tacc[c] = 0.f;
#pragma unroll
        for (int f = 0; f < 16; f++) {
            float fa = na[f], fb = nb[f];
#pragma unroll
            for (int c = 0; c < 16; c++)
                tacc[c] += fa * W2v[f*32 + cb + c] + fb * W2v[(16+f)*32 + cb + c];
        }
        float* row = V2 + (d*32 + ln) * 33 + cb;
#pragma unroll
        for (int c = 0; c < 16; c++) row[c] = tacc[c] * is32;
    }
    __syncthreads();
    if (w < 2) {
        int cb = w * 32 + h * 16;
        float tacc[16];
#pragma unroll
        for (int c = 0; c < 16; c++) tacc[c] = 0.f;
        const float* row = S2 + ln*65;
#pragma unroll
        for (int k = 0; k < 64; k++) {
            float sk = row[k];
#pragma unroll
            for (int c = 0; c < 16; c++) tacc[c] += sk * W3s[k*64 + cb + c];
        }
#pragma unroll
        for (int q = 0; q < 4; q++) {
            float4 r = {tacc[q*4+0]*0.125f, tacc[q*4+1]*0.125f,
                        tacc[q*4+2]*0.125f, tacc[q*4+3]*0.125f};
            ((float4*)(o + cb))[q] = r;
        }
    } else {
        int d = w - 2;
        int cb = h * 16;
        float tacc[16];
#pragma unroll
        for (int c = 0; c < 16; c++) tacc[c] = 0.f;
        const float* row = V2 + (d*32 + ln) * 33;
#pragma unroll
        for (int k = 0; k < 32; k++) {
            float vk = row[k];
#pragma unroll
            for (int c = 0; c < 16; c++) tacc[c] += vk * W3v[k*32 + cb + c];
        }
#pragma unroll
        for (int c = 0; c < 16; c++) o[64 + (cb+c)*3 + d] = tacc[c] * is32;
    }
}

extern "C" void kernel_launch(void* const* d_in, const int* in_sizes, int n_in,
                              void* d_out, int out_size, void* d_ws, size_t ws_size,
                              hipStream_t stream) {
    const float* x     = (const float*)d_in[0];
    const float* f_ij  = (const float*)d_in[1];
    const float* rcut  = (const float*)d_in[2];
    const float* Yr    = (const float*)d_in[3];
    const float* W1s   = (const float*)d_in[4];
    const float* W1v   = (const float*)d_in[5];
    const float* mW1   = (const float*)d_in[6];
    const float* mb1   = (const float*)d_in[7];
    const float* mW2   = (const float*)d_in[8];
    const float* mb2   = (const float*)d_in[9];
    const float* W2s   = (const float*)d_in[10];
    const float* W2v   = (const float*)d_in[11];
    const float* W3s   = (const float*)d_in[12];
    const float* W3v   = (const float*)d_in[13];
    const int*   idx_i = (const int*)d_in[14];
    const int*   idx_j = (const int*)d_in[15];
    float* out = (float*)d_out;

    // workspace layout (floats)
    float* fws   = (float*)d_ws;
    float* embed = fws;                                  // N*64
    float* acc   = embed + (size_t)NN * 64;              // N*128
    float* epack = acc   + (size_t)NN * 128;             // E*RSTR
    int* ibase   = (int*)(epack + (size_t)NE * RSTR);
    int* counts  = ibase;                                // N
    int* start   = counts + NN;                          // N+1
    int* rank    = start + NN + 1;                       // E
    int* order   = rank + NE;                            // N

    hipMemsetAsync(counts, 0, (size_t)NN * sizeof(int), stream);
    hist_kernel<<<NE/256, 256, 0, stream>>>(idx_i, counts, rank);
    scan_kernel<<<1, 1024, 0, stream>>>(counts, start, order);
    pack_kernel<<<NE/256, 256, 0, stream>>>(f_ij, rcut, Yr, idx_i, idx_j,
                                            mW1, mb1, start, rank, epack);
    embed_kernel<<<NN/256, 256, 0, stream>>>(x, W1s, W1v, embed);
    nodeagg_kernel<<<(NN*16)/256, 256, 0, stream>>>(embed, epack, start, order,
                                                    mW2, mb2, acc);
    out_kernel<<<NN/32, 320, 0, stream>>>(acc, W2s, W2v, W3s, W3v, out);
}